// Round 1
// baseline (6586.262 us; speedup 1.0000x reference)
//
#include <hip/hip_runtime.h>
#include <hip/hip_bf16.h>
#include <stdint.h>

#define E_N 16
#define TOPK 4
#define DD 2560
#define FF 1664
#define FSS 3328
#define TT 2048

#define BM 128
#define BN 128
#define BK 32
#define LDA 40                 // BK + 8 pad, ushorts per LDS row
#define TILE_US (128 * LDA)    // 5120 ushorts per tile matrix

typedef __attribute__((ext_vector_type(8))) __bf16 bf16x8;
typedef __attribute__((ext_vector_type(4))) float f32x4;

static_assert(DD % BK == 0 && FF % BK == 0 && FSS % BK == 0, "K divisibility");
static_assert(FF % BN == 0 && DD % BN == 0 && FSS % BN == 0, "N divisibility");
static_assert(TT % BM == 0, "M divisibility");

__device__ __forceinline__ unsigned short f2bf(float f) {
  return __builtin_bit_cast(unsigned short, (__bf16)f);
}
__device__ __forceinline__ unsigned int pk2(float a, float b) {
  return (unsigned int)f2bf(a) | ((unsigned int)f2bf(b) << 16);
}

// ---------------- X -> bf16 ----------------
__global__ __launch_bounds__(256) void cvt_bf16_kernel(const float* __restrict__ in,
                                                       unsigned short* __restrict__ out) {
  size_t i = ((size_t)blockIdx.x * 256 + threadIdx.x) * 4;
  float4 v = *reinterpret_cast<const float4*>(in + i);
  ushort4 o;
  o.x = f2bf(v.x); o.y = f2bf(v.y); o.z = f2bf(v.z); o.w = f2bf(v.w);
  *reinterpret_cast<ushort4*>(out + i) = o;
}

// ---------------- Router ----------------
__global__ __launch_bounds__(256) void router_kernel(const float* __restrict__ x,
                                                     const float* __restrict__ rw,
                                                     int* __restrict__ cnt,
                                                     int* __restrict__ list,
                                                     float* __restrict__ tw) {
  int t = blockIdx.x;
  const float* xr = x + (size_t)t * DD;
  __shared__ float logits[E_N];
  int lane = threadIdx.x & 63, wid = threadIdx.x >> 6;
  for (int ee = 0; ee < 4; ++ee) {
    int e = wid * 4 + ee;
    const float* wr = rw + (size_t)e * DD;
    float p = 0.f;
    for (int d = lane; d < DD; d += 64) p += xr[d] * wr[d];
#pragma unroll
    for (int off = 32; off > 0; off >>= 1) p += __shfl_down(p, off);
    if (lane == 0) logits[e] = p;
  }
  __syncthreads();
  if (threadIdx.x == 0) {
    float mx = -1e30f;
    for (int e = 0; e < E_N; ++e) mx = fmaxf(mx, logits[e]);
    float pe[E_N];
    for (int e = 0; e < E_N; ++e) pe[e] = __expf(logits[e] - mx);
    int idx[TOPK]; float val[TOPK]; float s4 = 0.f;
    unsigned used = 0;
    for (int k = 0; k < TOPK; ++k) {
      int bi = 0; float bv = -1.f;
      for (int e = 0; e < E_N; ++e)
        if (!((used >> e) & 1) && pe[e] > bv) { bv = pe[e]; bi = e; }
      used |= 1u << bi; idx[k] = bi; val[k] = bv; s4 += bv;
    }
    float inv = 1.f / s4;
    for (int k = 0; k < TOPK; ++k) {
      int e2 = idx[k];
      int pos = atomicAdd(&cnt[e2], 1);
      list[e2 * TT + pos] = t * 4 + k;
      tw[t * 4 + k] = val[k] * inv;
    }
  }
}

// ---------------- fused gate+up grouped GEMM ----------------
// A rows gathered from Xb via list codes (code>>2 = token); H written at row=code.
__global__ __launch_bounds__(256, 2) void gateup_kernel(
    const unsigned short* __restrict__ Xb,   // [*, Ktot] bf16
    const float* __restrict__ WgAll,         // [E][Ktot][Ntot] f32
    const float* __restrict__ WuAll,
    unsigned short* __restrict__ H,          // [*, Ntot] bf16
    const int* __restrict__ list,            // [E][TT] codes, or null
    const int* __restrict__ cnt,             // [E] or null
    int Ktot, int Ntot, int Mfixed) {
  int e = blockIdx.z;
  int M = cnt ? cnt[e] : Mfixed;
  int m0 = blockIdx.x * BM;
  if (m0 >= M) return;
  int n0 = blockIdx.y * BN;
  const float* Wg = WgAll + (size_t)e * Ktot * Ntot;
  const float* Wu = WuAll + (size_t)e * Ktot * Ntot;
  const int* lst = list ? (list + e * TT) : nullptr;

  __shared__ __align__(16) unsigned short lds[2][3 * TILE_US];

  int tid = threadIdx.x;
  // A staging: thread -> (row ra & ra+64, 8-elem chunk ca)
  int ra = tid >> 2;
  int ca = (tid & 3) * 8;
  int r0 = m0 + ra, r1 = r0 + 64;
  int rc0 = min(r0, M - 1), rc1 = min(r1, M - 1);
  int tok0 = lst ? (lst[rc0] >> 2) : rc0;
  int tok1 = lst ? (lst[rc1] >> 2) : rc1;
  const unsigned short* pA0 = Xb + (size_t)tok0 * Ktot + ca;
  const unsigned short* pA1 = Xb + (size_t)tok1 * Ktot + ca;
  // B staging: thread -> (col fb, k half kb)
  int fb = tid & 127;
  int kb = (tid >> 7) * 16;
  const float* pBg = Wg + (size_t)kb * Ntot + n0 + fb;
  const float* pBu = Wu + (size_t)kb * Ntot + n0 + fb;

  uint4 rA0, rA1;
  float rG[16], rU[16];

  int lane = tid & 63, wid = tid >> 6;
  int wr = (wid >> 1) * 64, wc = (wid & 1) * 64;
  int aoff = (wr + (lane & 15)) * LDA + (lane >> 4) * 8;
  int boff = (wc + (lane & 15)) * LDA + (lane >> 4) * 8;

  f32x4 accG[4][4] = {};
  f32x4 accU[4][4] = {};

  auto loadT = [&](int kt) {
    rA0 = *reinterpret_cast<const uint4*>(pA0 + (size_t)kt * BK);
    rA1 = *reinterpret_cast<const uint4*>(pA1 + (size_t)kt * BK);
    size_t bo = (size_t)kt * BK * Ntot;
#pragma unroll
    for (int j = 0; j < 16; ++j) rG[j] = pBg[bo + (size_t)j * Ntot];
#pragma unroll
    for (int j = 0; j < 16; ++j) rU[j] = pBu[bo + (size_t)j * Ntot];
  };
  auto storeT = [&](int b) {
    unsigned short* A = lds[b];
    unsigned short* Bg = A + TILE_US;
    unsigned short* Bu = A + 2 * TILE_US;
    *reinterpret_cast<uint4*>(A + ra * LDA + ca) = rA0;
    *reinterpret_cast<uint4*>(A + (ra + 64) * LDA + ca) = rA1;
    uint4 g0{pk2(rG[0], rG[1]), pk2(rG[2], rG[3]), pk2(rG[4], rG[5]), pk2(rG[6], rG[7])};
    uint4 g1{pk2(rG[8], rG[9]), pk2(rG[10], rG[11]), pk2(rG[12], rG[13]), pk2(rG[14], rG[15])};
    uint4 u0{pk2(rU[0], rU[1]), pk2(rU[2], rU[3]), pk2(rU[4], rU[5]), pk2(rU[6], rU[7])};
    uint4 u1{pk2(rU[8], rU[9]), pk2(rU[10], rU[11]), pk2(rU[12], rU[13]), pk2(rU[14], rU[15])};
    *reinterpret_cast<uint4*>(Bg + fb * LDA + kb) = g0;
    *reinterpret_cast<uint4*>(Bg + fb * LDA + kb + 8) = g1;
    *reinterpret_cast<uint4*>(Bu + fb * LDA + kb) = u0;
    *reinterpret_cast<uint4*>(Bu + fb * LDA + kb + 8) = u1;
  };

  int nk = Ktot / BK;
  loadT(0);
  storeT(0);
  __syncthreads();
  for (int kt = 0; kt < nk; ++kt) {
    int b = kt & 1;
    if (kt + 1 < nk) loadT(kt + 1);
    const unsigned short* A = lds[b];
    const unsigned short* Bg = A + TILE_US;
    const unsigned short* Bu = A + 2 * TILE_US;
    bf16x8 af[4], bg[4], bu[4];
#pragma unroll
    for (int m = 0; m < 4; ++m)
      af[m] = __builtin_bit_cast(bf16x8, *reinterpret_cast<const uint4*>(A + aoff + m * 16 * LDA));
#pragma unroll
    for (int n = 0; n < 4; ++n) {
      bg[n] = __builtin_bit_cast(bf16x8, *reinterpret_cast<const uint4*>(Bg + boff + n * 16 * LDA));
      bu[n] = __builtin_bit_cast(bf16x8, *reinterpret_cast<const uint4*>(Bu + boff + n * 16 * LDA));
    }
#pragma unroll
    for (int m = 0; m < 4; ++m)
#pragma unroll
      for (int n = 0; n < 4; ++n) {
        accG[m][n] = __builtin_amdgcn_mfma_f32_16x16x32_bf16(af[m], bg[n], accG[m][n], 0, 0, 0);
        accU[m][n] = __builtin_amdgcn_mfma_f32_16x16x32_bf16(af[m], bu[n], accU[m][n], 0, 0, 0);
      }
    if (kt + 1 < nk) storeT(b ^ 1);
    __syncthreads();
  }

  // epilogue: h = silu(g)*u -> bf16
#pragma unroll
  for (int m = 0; m < 4; ++m) {
#pragma unroll
    for (int r = 0; r < 4; ++r) {
      int lr = wr + m * 16 + (lane >> 4) * 4 + r;
      int grow = m0 + lr;
      if (grow < M) {
        int code = lst ? lst[grow] : grow;
        unsigned short* Hp = H + (size_t)code * Ntot + n0 + wc + (lane & 15);
#pragma unroll
        for (int n = 0; n < 4; ++n) {
          float g = accG[m][n][r], u = accU[m][n][r];
          float h = (g / (1.f + __expf(-g))) * u;
          Hp[n * 16] = f2bf(h);
        }
      }
    }
  }
}

// ---------------- down grouped GEMM ----------------
// A rows gathered from Hb at row=code; Y written at row=code, scaled by tw[code].
__global__ __launch_bounds__(256, 2) void down_kernel(
    const unsigned short* __restrict__ Hb,   // [*, Ktot] bf16
    const float* __restrict__ WAll,          // [E][Ktot][Ntot] f32
    float* __restrict__ Y,                   // [*, Ntot] f32
    const int* __restrict__ list,
    const int* __restrict__ cnt,
    const float* __restrict__ tw,            // [4*TT] or null
    int Ktot, int Ntot, int Mfixed) {
  int e = blockIdx.z;
  int M = cnt ? cnt[e] : Mfixed;
  int m0 = blockIdx.x * BM;
  if (m0 >= M) return;
  int n0 = blockIdx.y * BN;
  const float* W = WAll + (size_t)e * Ktot * Ntot;
  const int* lst = list ? (list + e * TT) : nullptr;

  __shared__ __align__(16) unsigned short lds[2][2 * TILE_US];

  int tid = threadIdx.x;
  int ra = tid >> 2;
  int ca = (tid & 3) * 8;
  int r0 = m0 + ra, r1 = r0 + 64;
  int rc0 = min(r0, M - 1), rc1 = min(r1, M - 1);
  int row0 = lst ? lst[rc0] : rc0;
  int row1 = lst ? lst[rc1] : rc1;
  const unsigned short* pA0 = Hb + (size_t)row0 * Ktot + ca;
  const unsigned short* pA1 = Hb + (size_t)row1 * Ktot + ca;
  int fb = tid & 127;
  int kb = (tid >> 7) * 16;
  const float* pB = W + (size_t)kb * Ntot + n0 + fb;

  uint4 rA0, rA1;
  float rB[16];

  int lane = tid & 63, wid = tid >> 6;
  int wr = (wid >> 1) * 64, wc = (wid & 1) * 64;
  int aoff = (wr + (lane & 15)) * LDA + (lane >> 4) * 8;
  int boff = (wc + (lane & 15)) * LDA + (lane >> 4) * 8;

  f32x4 acc[4][4] = {};

  auto loadT = [&](int kt) {
    rA0 = *reinterpret_cast<const uint4*>(pA0 + (size_t)kt * BK);
    rA1 = *reinterpret_cast<const uint4*>(pA1 + (size_t)kt * BK);
    size_t bo = (size_t)kt * BK * Ntot;
#pragma unroll
    for (int j = 0; j < 16; ++j) rB[j] = pB[bo + (size_t)j * Ntot];
  };
  auto storeT = [&](int b) {
    unsigned short* A = lds[b];
    unsigned short* Bs = A + TILE_US;
    *reinterpret_cast<uint4*>(A + ra * LDA + ca) = rA0;
    *reinterpret_cast<uint4*>(A + (ra + 64) * LDA + ca) = rA1;
    uint4 b0{pk2(rB[0], rB[1]), pk2(rB[2], rB[3]), pk2(rB[4], rB[5]), pk2(rB[6], rB[7])};
    uint4 b1{pk2(rB[8], rB[9]), pk2(rB[10], rB[11]), pk2(rB[12], rB[13]), pk2(rB[14], rB[15])};
    *reinterpret_cast<uint4*>(Bs + fb * LDA + kb) = b0;
    *reinterpret_cast<uint4*>(Bs + fb * LDA + kb + 8) = b1;
  };

  int nk = Ktot / BK;
  loadT(0);
  storeT(0);
  __syncthreads();
  for (int kt = 0; kt < nk; ++kt) {
    int b = kt & 1;
    if (kt + 1 < nk) loadT(kt + 1);
    const unsigned short* A = lds[b];
    const unsigned short* Bs = A + TILE_US;
    bf16x8 af[4], bf[4];
#pragma unroll
    for (int m = 0; m < 4; ++m)
      af[m] = __builtin_bit_cast(bf16x8, *reinterpret_cast<const uint4*>(A + aoff + m * 16 * LDA));
#pragma unroll
    for (int n = 0; n < 4; ++n)
      bf[n] = __builtin_bit_cast(bf16x8, *reinterpret_cast<const uint4*>(Bs + boff + n * 16 * LDA));
#pragma unroll
    for (int m = 0; m < 4; ++m)
#pragma unroll
      for (int n = 0; n < 4; ++n)
        acc[m][n] = __builtin_amdgcn_mfma_f32_16x16x32_bf16(af[m], bf[n], acc[m][n], 0, 0, 0);
    if (kt + 1 < nk) storeT(b ^ 1);
    __syncthreads();
  }

#pragma unroll
  for (int m = 0; m < 4; ++m) {
#pragma unroll
    for (int r = 0; r < 4; ++r) {
      int lr = wr + m * 16 + (lane >> 4) * 4 + r;
      int grow = m0 + lr;
      if (grow < M) {
        int code = lst ? lst[grow] : grow;
        float scale = tw ? tw[code] : 1.f;
        float* Yp = Y + (size_t)code * Ntot + n0 + wc + (lane & 15);
#pragma unroll
        for (int n = 0; n < 4; ++n) Yp[n * 16] = acc[m][n][r] * scale;
      }
    }
  }
}

// ---------------- combine ----------------
__global__ __launch_bounds__(256) void combine_kernel(const float* __restrict__ Y,
                                                      const float* __restrict__ Ys,
                                                      float* __restrict__ out) {
  size_t i = ((size_t)blockIdx.x * 256 + threadIdx.x) * 4;
  size_t t = i / DD;
  int d = (int)(i % DD);
  float4 a = *reinterpret_cast<const float4*>(Ys + i);
#pragma unroll
  for (int k = 0; k < 4; ++k) {
    float4 v = *reinterpret_cast<const float4*>(Y + (t * 4 + k) * (size_t)DD + d);
    a.x += v.x; a.y += v.y; a.z += v.z; a.w += v.w;
  }
  *reinterpret_cast<float4*>(out + i) = a;
}

extern "C" void kernel_launch(void* const* d_in, const int* in_sizes, int n_in,
                              void* d_out, int out_size, void* d_ws, size_t ws_size,
                              hipStream_t stream) {
  const float* x  = (const float*)d_in[0];
  const float* rw = (const float*)d_in[1];
  const float* wg = (const float*)d_in[2];
  const float* wu = (const float*)d_in[3];
  const float* wd = (const float*)d_in[4];
  const float* sg = (const float*)d_in[5];
  const float* su = (const float*)d_in[6];
  const float* sd = (const float*)d_in[7];
  float* out = (float*)d_out;

  char* ws = (char*)d_ws;
  size_t off = 0;
  auto alloc = [&](size_t bytes) {
    off = (off + 255) & ~(size_t)255;
    void* p = ws + off;
    off += bytes;
    return p;
  };
  unsigned short* Xb = (unsigned short*)alloc((size_t)TT * DD * 2);
  unsigned short* Hx = (unsigned short*)alloc((size_t)4 * TT * FF * 2);
  unsigned short* Hs = (unsigned short*)alloc((size_t)TT * FSS * 2);
  float* Y   = (float*)alloc((size_t)4 * TT * DD * 4);
  float* Ys  = (float*)alloc((size_t)TT * DD * 4);
  float* tw  = (float*)alloc((size_t)4 * TT * 4);
  int* cnt   = (int*)alloc(E_N * 4);
  int* list  = (int*)alloc((size_t)E_N * TT * 4);
  (void)ws_size; (void)in_sizes; (void)n_in; (void)out_size;

  hipMemsetAsync(cnt, 0, E_N * 4, stream);
  cvt_bf16_kernel<<<TT * DD / 4 / 256, 256, 0, stream>>>(x, Xb);
  router_kernel<<<TT, 256, 0, stream>>>(x, rw, cnt, list, tw);

  // expert gate+up: K=D, N=F
  gateup_kernel<<<dim3(TT / BM, FF / BN, E_N), 256, 0, stream>>>(
      Xb, wg, wu, Hx, list, cnt, DD, FF, 0);
  // shared gate+up: K=D, N=FS
  gateup_kernel<<<dim3(TT / BM, FSS / BN, 1), 256, 0, stream>>>(
      Xb, sg, su, Hs, nullptr, nullptr, DD, FSS, TT);
  // expert down: K=F, N=D (scaled by routing weight)
  down_kernel<<<dim3(TT / BM, DD / BN, E_N), 256, 0, stream>>>(
      Hx, wd, Y, list, cnt, tw, FF, DD, 0);
  // shared down: K=FS, N=D
  down_kernel<<<dim3(TT / BM, DD / BN, 1), 256, 0, stream>>>(
      Hs, sd, Ys, nullptr, nullptr, nullptr, FSS, DD, TT);

  combine_kernel<<<TT * DD / 4 / 256, 256, 0, stream>>>(Y, Ys, out);
}

// Round 2
// 1485.970 us; speedup vs baseline: 4.4323x; 4.4323x over previous
//
#include <hip/hip_runtime.h>
#include <hip/hip_bf16.h>
#include <stdint.h>

#define E_N 16
#define TOPK 4
#define DD 2560
#define FF 1664
#define FSS 3328
#define TT 2048

#define BM 128
#define BN 128
#define BK 64

typedef __attribute__((ext_vector_type(8))) __bf16 bf16x8;
typedef __attribute__((ext_vector_type(4))) float f32x4;

static_assert(DD % 64 == 0 && FF % 64 == 0 && FSS % 64 == 0, "64 divisibility");

__device__ __forceinline__ unsigned short f2bf(float f) {
  return __builtin_bit_cast(unsigned short, (__bf16)f);
}
__device__ __forceinline__ unsigned int pk2(float a, float b) {
  return (unsigned int)f2bf(a) | ((unsigned int)f2bf(b) << 16);
}

#define GLOAD16(g, l)                                                          \
  __builtin_amdgcn_global_load_lds(                                            \
      (const __attribute__((address_space(1))) void*)(g),                      \
      (__attribute__((address_space(3))) void*)(l), 16, 0, 0)

// ---------------- X -> bf16 ----------------
__global__ __launch_bounds__(256) void cvt_bf16_kernel(const float* __restrict__ in,
                                                       unsigned short* __restrict__ out) {
  size_t i = ((size_t)blockIdx.x * 256 + threadIdx.x) * 4;
  float4 v = *reinterpret_cast<const float4*>(in + i);
  ushort4 o;
  o.x = f2bf(v.x); o.y = f2bf(v.y); o.z = f2bf(v.z); o.w = f2bf(v.w);
  *reinterpret_cast<ushort4*>(out + i) = o;
}

// ---------------- weight transpose+convert: [K][N] f32 -> [N][K] bf16 ----------------
__global__ __launch_bounds__(256) void tcvt_kernel(const float* __restrict__ in,
                                                   unsigned short* __restrict__ out,
                                                   int K, int N) {
  __shared__ float lds[64 * 65];
  int z = blockIdx.z;
  in += (size_t)z * K * N;
  out += (size_t)z * K * N;
  int k0 = blockIdx.x * 64, n0 = blockIdx.y * 64;
  int t = threadIdx.x;
#pragma unroll
  for (int j = 0; j < 4; ++j) {
    int idx = j * 256 + t;
    int r = idx >> 4, c = (idx & 15) * 4;
    float4 v = *reinterpret_cast<const float4*>(in + (size_t)(k0 + r) * N + n0 + c);
    lds[r * 65 + c] = v.x;
    lds[r * 65 + c + 1] = v.y;
    lds[r * 65 + c + 2] = v.z;
    lds[r * 65 + c + 3] = v.w;
  }
  __syncthreads();
#pragma unroll
  for (int j = 0; j < 2; ++j) {
    int idx = j * 256 + t;
    int n = idx >> 3, kg = (idx & 7) * 8;
    float a0 = lds[(kg + 0) * 65 + n], a1 = lds[(kg + 1) * 65 + n];
    float a2 = lds[(kg + 2) * 65 + n], a3 = lds[(kg + 3) * 65 + n];
    float a4 = lds[(kg + 4) * 65 + n], a5 = lds[(kg + 5) * 65 + n];
    float a6 = lds[(kg + 6) * 65 + n], a7 = lds[(kg + 7) * 65 + n];
    uint4 o{pk2(a0, a1), pk2(a2, a3), pk2(a4, a5), pk2(a6, a7)};
    *reinterpret_cast<uint4*>(out + (size_t)(n0 + n) * K + k0 + kg) = o;
  }
}

// ---------------- Router ----------------
__global__ __launch_bounds__(256) void router_kernel(const float* __restrict__ x,
                                                     const float* __restrict__ rw,
                                                     int* __restrict__ cnt,
                                                     int* __restrict__ list,
                                                     float* __restrict__ tw) {
  int t = blockIdx.x;
  const float* xr = x + (size_t)t * DD;
  __shared__ float logits[E_N];
  int lane = threadIdx.x & 63, wid = threadIdx.x >> 6;
  for (int ee = 0; ee < 4; ++ee) {
    int e = wid * 4 + ee;
    const float* wr = rw + (size_t)e * DD;
    float p = 0.f;
    for (int d = lane; d < DD; d += 64) p += xr[d] * wr[d];
#pragma unroll
    for (int off = 32; off > 0; off >>= 1) p += __shfl_down(p, off);
    if (lane == 0) logits[e] = p;
  }
  __syncthreads();
  if (threadIdx.x == 0) {
    float mx = -1e30f;
    for (int e = 0; e < E_N; ++e) mx = fmaxf(mx, logits[e]);
    float pe[E_N];
    for (int e = 0; e < E_N; ++e) pe[e] = __expf(logits[e] - mx);
    int idx[TOPK]; float val[TOPK]; float s4 = 0.f;
    unsigned used = 0;
    for (int k = 0; k < TOPK; ++k) {
      int bi = 0; float bv = -1.f;
      for (int e = 0; e < E_N; ++e)
        if (!((used >> e) & 1) && pe[e] > bv) { bv = pe[e]; bi = e; }
      used |= 1u << bi; idx[k] = bi; val[k] = bv; s4 += bv;
    }
    float inv = 1.f / s4;
    for (int k = 0; k < TOPK; ++k) {
      int e2 = idx[k];
      int pos = atomicAdd(&cnt[e2], 1);
      list[e2 * TT + pos] = t * 4 + k;
      tw[t * 4 + k] = val[k] * inv;
    }
  }
}

// ---------------- fused gate+up grouped GEMM (bf16 weights, transposed [N][K]) --------
__global__ __launch_bounds__(256, 2) void gu_kernel(
    const unsigned short* __restrict__ Xb,   // [T][Ktot] bf16
    const unsigned short* __restrict__ WgT,  // [E][Ntot][Ktot] bf16
    const unsigned short* __restrict__ WuT,
    unsigned short* __restrict__ H,          // [codes][Ntot] bf16
    const int* __restrict__ list, const int* __restrict__ cnt,
    int Ktot, int Ntot, int Mfixed) {
  int e = blockIdx.z;
  int M = cnt ? cnt[e] : Mfixed;
  int m0 = blockIdx.x * BM;
  if (m0 >= M) return;
  int n0 = blockIdx.y * BN;
  const unsigned short* Bg0 = WgT + (size_t)e * Ktot * Ntot;
  const unsigned short* Bu0 = WuT + (size_t)e * Ktot * Ntot;
  const int* lst = list ? (list + e * TT) : nullptr;

  __shared__ __align__(16) unsigned short lds[3 * BM * BK];
  unsigned short* ldsA = lds;
  unsigned short* ldsG = lds + BM * BK;
  unsigned short* ldsU = lds + 2 * BM * BK;

  int tid = threadIdx.x, lane = tid & 63, w = tid >> 6;

  // staging: issue J = w*4+q covers LDS rows J*8..J*8+7 (row-linear dest),
  // per-lane global source pre-swizzled: chunk c -> c ^ (row&7)
  const unsigned short* pA[4];
  const unsigned short* pG[4];
  const unsigned short* pU[4];
#pragma unroll
  for (int q = 0; q < 4; ++q) {
    int J = w * 4 + q;
    int row = J * 8 + (lane >> 3);
    int c = lane & 7;
    int cs = c ^ (row & 7);
    int ar = min(m0 + row, M - 1);
    int code = lst ? lst[ar] : ar;
    int tok = lst ? (code >> 2) : code;
    pA[q] = Xb + (size_t)tok * Ktot + cs * 8;
    pG[q] = Bg0 + (size_t)(n0 + row) * Ktot + cs * 8;
    pU[q] = Bu0 + (size_t)(n0 + row) * Ktot + cs * 8;
  }

  auto issue = [&](int kt) {
    int koff = kt * BK;
#pragma unroll
    for (int q = 0; q < 4; ++q) {
      int J = w * 4 + q;
      GLOAD16(pA[q] + koff, ldsA + J * 512);
      GLOAD16(pG[q] + koff, ldsG + J * 512);
      GLOAD16(pU[q] + koff, ldsU + J * 512);
    }
  };

  int wr = (w >> 1) * 64, wc = (w & 1) * 64;
  // fragment LDS ushort-offsets (swizzled read, matches source pre-swizzle)
  int aoff[4][2], boff[4][2];
#pragma unroll
  for (int m = 0; m < 4; ++m) {
    int r = wr + m * 16 + (lane & 15);
    int rb = wc + m * 16 + (lane & 15);
#pragma unroll
    for (int kh = 0; kh < 2; ++kh) {
      int cg = kh * 4 + (lane >> 4);
      aoff[m][kh] = r * BK + ((cg ^ (r & 7)) * 8);
      boff[m][kh] = rb * BK + ((cg ^ (rb & 7)) * 8);
    }
  }

  f32x4 accG[4][4] = {};
  f32x4 accU[4][4] = {};

  int nk = Ktot / BK;
  issue(0);
  for (int kt = 0; kt < nk; ++kt) {
    __syncthreads();  // drains vmcnt(0): tile ready for all waves
#pragma unroll
    for (int kh = 0; kh < 2; ++kh) {
      bf16x8 a[4], g[4], u[4];
#pragma unroll
      for (int m = 0; m < 4; ++m)
        a[m] = __builtin_bit_cast(bf16x8, *reinterpret_cast<const uint4*>(ldsA + aoff[m][kh]));
#pragma unroll
      for (int n = 0; n < 4; ++n) {
        g[n] = __builtin_bit_cast(bf16x8, *reinterpret_cast<const uint4*>(ldsG + boff[n][kh]));
        u[n] = __builtin_bit_cast(bf16x8, *reinterpret_cast<const uint4*>(ldsU + boff[n][kh]));
      }
#pragma unroll
      for (int m = 0; m < 4; ++m)
#pragma unroll
        for (int n = 0; n < 4; ++n) {
          accG[m][n] = __builtin_amdgcn_mfma_f32_16x16x32_bf16(a[m], g[n], accG[m][n], 0, 0, 0);
          accU[m][n] = __builtin_amdgcn_mfma_f32_16x16x32_bf16(a[m], u[n], accU[m][n], 0, 0, 0);
        }
    }
    __syncthreads();  // all waves done reading tile
    if (kt + 1 < nk) issue(kt + 1);
  }

  // epilogue: h = silu(g)*u -> bf16 at row=code
#pragma unroll
  for (int m = 0; m < 4; ++m) {
#pragma unroll
    for (int r = 0; r < 4; ++r) {
      int lr = wr + m * 16 + (lane >> 4) * 4 + r;
      int grow = m0 + lr;
      if (grow < M) {
        int code = lst ? lst[grow] : grow;
        unsigned short* Hp = H + (size_t)code * Ntot + n0 + wc + (lane & 15);
#pragma unroll
        for (int n = 0; n < 4; ++n) {
          float gg = accG[m][n][r], uu = accU[m][n][r];
          Hp[n * 16] = f2bf((gg / (1.f + __expf(-gg))) * uu);
        }
      }
    }
  }
}

// ---------------- down grouped GEMM ----------------
__global__ __launch_bounds__(256, 2) void dn_kernel(
    const unsigned short* __restrict__ Hb,   // [codes][Ktot] bf16
    const unsigned short* __restrict__ WT,   // [E][Ntot][Ktot] bf16
    float* __restrict__ Y,                   // [codes][Ntot] f32
    const int* __restrict__ list, const int* __restrict__ cnt,
    const float* __restrict__ tw, int Ktot, int Ntot, int Mfixed) {
  int e = blockIdx.z;
  int M = cnt ? cnt[e] : Mfixed;
  int m0 = blockIdx.x * BM;
  if (m0 >= M) return;
  int n0 = blockIdx.y * BN;
  const unsigned short* B0 = WT + (size_t)e * Ktot * Ntot;
  const int* lst = list ? (list + e * TT) : nullptr;

  __shared__ __align__(16) unsigned short lds[2 * BM * BK];
  unsigned short* ldsA = lds;
  unsigned short* ldsB = lds + BM * BK;

  int tid = threadIdx.x, lane = tid & 63, w = tid >> 6;

  const unsigned short* pA[4];
  const unsigned short* pB[4];
#pragma unroll
  for (int q = 0; q < 4; ++q) {
    int J = w * 4 + q;
    int row = J * 8 + (lane >> 3);
    int c = lane & 7;
    int cs = c ^ (row & 7);
    int ar = min(m0 + row, M - 1);
    int code = lst ? lst[ar] : ar;
    pA[q] = Hb + (size_t)code * Ktot + cs * 8;
    pB[q] = B0 + (size_t)(n0 + row) * Ktot + cs * 8;
  }

  auto issue = [&](int kt) {
    int koff = kt * BK;
#pragma unroll
    for (int q = 0; q < 4; ++q) {
      int J = w * 4 + q;
      GLOAD16(pA[q] + koff, ldsA + J * 512);
      GLOAD16(pB[q] + koff, ldsB + J * 512);
    }
  };

  int wr = (w >> 1) * 64, wc = (w & 1) * 64;
  int aoff[4][2], boff[4][2];
#pragma unroll
  for (int m = 0; m < 4; ++m) {
    int r = wr + m * 16 + (lane & 15);
    int rb = wc + m * 16 + (lane & 15);
#pragma unroll
    for (int kh = 0; kh < 2; ++kh) {
      int cg = kh * 4 + (lane >> 4);
      aoff[m][kh] = r * BK + ((cg ^ (r & 7)) * 8);
      boff[m][kh] = rb * BK + ((cg ^ (rb & 7)) * 8);
    }
  }

  f32x4 acc[4][4] = {};

  int nk = Ktot / BK;
  issue(0);
  for (int kt = 0; kt < nk; ++kt) {
    __syncthreads();
#pragma unroll
    for (int kh = 0; kh < 2; ++kh) {
      bf16x8 a[4], b[4];
#pragma unroll
      for (int m = 0; m < 4; ++m)
        a[m] = __builtin_bit_cast(bf16x8, *reinterpret_cast<const uint4*>(ldsA + aoff[m][kh]));
#pragma unroll
      for (int n = 0; n < 4; ++n)
        b[n] = __builtin_bit_cast(bf16x8, *reinterpret_cast<const uint4*>(ldsB + boff[n][kh]));
#pragma unroll
      for (int m = 0; m < 4; ++m)
#pragma unroll
        for (int n = 0; n < 4; ++n)
          acc[m][n] = __builtin_amdgcn_mfma_f32_16x16x32_bf16(a[m], b[n], acc[m][n], 0, 0, 0);
    }
    __syncthreads();
    if (kt + 1 < nk) issue(kt + 1);
  }

#pragma unroll
  for (int m = 0; m < 4; ++m) {
#pragma unroll
    for (int r = 0; r < 4; ++r) {
      int lr = wr + m * 16 + (lane >> 4) * 4 + r;
      int grow = m0 + lr;
      if (grow < M) {
        int code = lst ? lst[grow] : grow;
        float scale = tw ? tw[code] : 1.f;
        float* Yp = Y + (size_t)code * Ntot + n0 + wc + (lane & 15);
#pragma unroll
        for (int n = 0; n < 4; ++n) Yp[n * 16] = acc[m][n][r] * scale;
      }
    }
  }
}

// ---------------- combine ----------------
__global__ __launch_bounds__(256) void combine_kernel(const float* __restrict__ Y,
                                                      const float* __restrict__ Ys,
                                                      float* __restrict__ out) {
  size_t i = ((size_t)blockIdx.x * 256 + threadIdx.x) * 4;
  size_t t = i / DD;
  int d = (int)(i % DD);
  float4 a = *reinterpret_cast<const float4*>(Ys + i);
#pragma unroll
  for (int k = 0; k < 4; ++k) {
    float4 v = *reinterpret_cast<const float4*>(Y + (t * 4 + k) * (size_t)DD + d);
    a.x += v.x; a.y += v.y; a.z += v.z; a.w += v.w;
  }
  *reinterpret_cast<float4*>(out + i) = a;
}

extern "C" void kernel_launch(void* const* d_in, const int* in_sizes, int n_in,
                              void* d_out, int out_size, void* d_ws, size_t ws_size,
                              hipStream_t stream) {
  const float* x  = (const float*)d_in[0];
  const float* rw = (const float*)d_in[1];
  const float* wg = (const float*)d_in[2];
  const float* wu = (const float*)d_in[3];
  const float* wd = (const float*)d_in[4];
  const float* sg = (const float*)d_in[5];
  const float* su = (const float*)d_in[6];
  const float* sd = (const float*)d_in[7];
  float* out = (float*)d_out;

  char* ws = (char*)d_ws;
  size_t off = 0;
  auto alloc = [&](size_t bytes) {
    off = (off + 255) & ~(size_t)255;
    void* p = ws + off;
    off += bytes;
    return p;
  };
  // W1/W2 are reused: WgT/WuT for gateup phase, then WdT/SdT for down phase.
  unsigned short* W1 = (unsigned short*)alloc((size_t)E_N * FF * DD * 2);   // 136 MB
  unsigned short* W2 = (unsigned short*)alloc((size_t)E_N * FF * DD * 2);   // 136 MB
  unsigned short* W3 = (unsigned short*)alloc((size_t)FSS * DD * 2);        // 17 MB
  unsigned short* W4 = (unsigned short*)alloc((size_t)FSS * DD * 2);        // 17 MB
  unsigned short* Xb = (unsigned short*)alloc((size_t)TT * DD * 2);
  unsigned short* Hx = (unsigned short*)alloc((size_t)4 * TT * FF * 2);
  unsigned short* Hs = (unsigned short*)alloc((size_t)TT * FSS * 2);
  float* Y  = (float*)alloc((size_t)4 * TT * DD * 4);
  float* Ys = (float*)alloc((size_t)TT * DD * 4);
  float* tw = (float*)alloc((size_t)4 * TT * 4);
  int* cnt  = (int*)alloc(E_N * 4);
  int* list = (int*)alloc((size_t)E_N * TT * 4);
  (void)ws_size; (void)in_sizes; (void)n_in; (void)out_size;

  hipMemsetAsync(cnt, 0, E_N * 4, stream);
  cvt_bf16_kernel<<<TT * DD / 4 / 256, 256, 0, stream>>>(x, Xb);
  router_kernel<<<TT, 256, 0, stream>>>(x, rw, cnt, list, tw);

  // --- gate/up weight transposes: [D][F(S)] -> [F(S)][D] bf16 ---
  tcvt_kernel<<<dim3(DD / 64, FF / 64, E_N), 256, 0, stream>>>(wg, W1, DD, FF);
  tcvt_kernel<<<dim3(DD / 64, FF / 64, E_N), 256, 0, stream>>>(wu, W2, DD, FF);
  tcvt_kernel<<<dim3(DD / 64, FSS / 64, 1), 256, 0, stream>>>(sg, W3, DD, FSS);
  tcvt_kernel<<<dim3(DD / 64, FSS / 64, 1), 256, 0, stream>>>(su, W4, DD, FSS);

  // --- gate+up GEMMs ---
  gu_kernel<<<dim3(TT / BM, FF / BN, E_N), 256, 0, stream>>>(
      Xb, W1, W2, Hx, list, cnt, DD, FF, 0);
  gu_kernel<<<dim3(TT / BM, FSS / BN, 1), 256, 0, stream>>>(
      Xb, W3, W4, Hs, nullptr, nullptr, DD, FSS, TT);

  // --- down weight transposes: [F(S)][D] -> [D][F(S)] bf16 (reuse W1/W2) ---
  tcvt_kernel<<<dim3(FF / 64, DD / 64, E_N), 256, 0, stream>>>(wd, W1, FF, DD);
  tcvt_kernel<<<dim3(FSS / 64, DD / 64, 1), 256, 0, stream>>>(sd, W2, FSS, DD);

  // --- down GEMMs ---
  dn_kernel<<<dim3(TT / BM, DD / BN, E_N), 256, 0, stream>>>(
      Hx, W1, Y, list, cnt, tw, FF, DD, 0);
  dn_kernel<<<dim3(TT / BM, DD / BN, 1), 256, 0, stream>>>(
      Hs, W2, Ys, nullptr, nullptr, nullptr, FSS, DD, TT);

  combine_kernel<<<TT * DD / 4 / 256, 256, 0, stream>>>(Y, Ys, out);
}

// Round 3
// 1035.571 us; speedup vs baseline: 6.3600x; 1.4349x over previous
//
#include <hip/hip_runtime.h>
#include <hip/hip_bf16.h>
#include <stdint.h>

#define E_N 16
#define TOPK 4
#define DD 2560
#define FF 1664
#define FSS 3328
#define TT 2048

#define BM 128
#define BN 128
#define BK 32

typedef __attribute__((ext_vector_type(8))) __bf16 bf16x8;
typedef __attribute__((ext_vector_type(4))) float f32x4;

static_assert(DD % 64 == 0 && FF % 64 == 0 && FSS % 64 == 0, "64 divisibility");

__device__ __forceinline__ unsigned short f2bf(float f) {
  return __builtin_bit_cast(unsigned short, (__bf16)f);
}
__device__ __forceinline__ unsigned int pk2(float a, float b) {
  return (unsigned int)f2bf(a) | ((unsigned int)f2bf(b) << 16);
}

#define GLOAD16(g, l)                                                          \
  __builtin_amdgcn_global_load_lds(                                            \
      (const __attribute__((address_space(1))) void*)(g),                      \
      (__attribute__((address_space(3))) void*)(l), 16, 0, 0)

#define SBAR() __builtin_amdgcn_s_barrier()
#define SCHED0() __builtin_amdgcn_sched_barrier(0)
#define VMW(N) asm volatile("s_waitcnt vmcnt(" #N ")" ::: "memory")

// swizzled block decompose: XCD-chunked bijective remap (requires nwg%8==0)
__device__ __forceinline__ void swz_block(int& bm, int& bn, int& bz) {
  int gx = gridDim.x, gy = gridDim.y;
  int nwg = gx * gy * gridDim.z;
  int flat = blockIdx.x + gx * (blockIdx.y + gy * blockIdx.z);
  if ((nwg & 7) == 0) flat = (flat & 7) * (nwg >> 3) + (flat >> 3);
  bm = flat % gx;
  int rest = flat / gx;
  bn = rest % gy;
  bz = rest / gy;
}

// ---------------- X -> bf16 ----------------
__global__ __launch_bounds__(256) void cvt_bf16_kernel(const float* __restrict__ in,
                                                       unsigned short* __restrict__ out) {
  size_t i = ((size_t)blockIdx.x * 256 + threadIdx.x) * 4;
  float4 v = *reinterpret_cast<const float4*>(in + i);
  ushort4 o;
  o.x = f2bf(v.x); o.y = f2bf(v.y); o.z = f2bf(v.z); o.w = f2bf(v.w);
  *reinterpret_cast<ushort4*>(out + i) = o;
}

// ---------------- weight transpose+convert: [K][N] f32 -> [N][K] bf16 ----------------
__global__ __launch_bounds__(256) void tcvt_kernel(const float* __restrict__ in,
                                                   unsigned short* __restrict__ out,
                                                   int K, int N) {
  __shared__ float lds[64 * 65];
  int z = blockIdx.z;
  in += (size_t)z * K * N;
  out += (size_t)z * K * N;
  int k0 = blockIdx.x * 64, n0 = blockIdx.y * 64;
  int t = threadIdx.x;
#pragma unroll
  for (int j = 0; j < 4; ++j) {
    int idx = j * 256 + t;
    int r = idx >> 4, c = (idx & 15) * 4;
    float4 v = *reinterpret_cast<const float4*>(in + (size_t)(k0 + r) * N + n0 + c);
    lds[r * 65 + c] = v.x;
    lds[r * 65 + c + 1] = v.y;
    lds[r * 65 + c + 2] = v.z;
    lds[r * 65 + c + 3] = v.w;
  }
  __syncthreads();
#pragma unroll
  for (int j = 0; j < 2; ++j) {
    int idx = j * 256 + t;
    int n = idx >> 3, kg = (idx & 7) * 8;
    float a0 = lds[(kg + 0) * 65 + n], a1 = lds[(kg + 1) * 65 + n];
    float a2 = lds[(kg + 2) * 65 + n], a3 = lds[(kg + 3) * 65 + n];
    float a4 = lds[(kg + 4) * 65 + n], a5 = lds[(kg + 5) * 65 + n];
    float a6 = lds[(kg + 6) * 65 + n], a7 = lds[(kg + 7) * 65 + n];
    uint4 o{pk2(a0, a1), pk2(a2, a3), pk2(a4, a5), pk2(a6, a7)};
    *reinterpret_cast<uint4*>(out + (size_t)(n0 + n) * K + k0 + kg) = o;
  }
}

// ---------------- Router ----------------
__global__ __launch_bounds__(256) void router_kernel(const float* __restrict__ x,
                                                     const float* __restrict__ rw,
                                                     int* __restrict__ cnt,
                                                     int* __restrict__ list,
                                                     float* __restrict__ tw) {
  int t = blockIdx.x;
  const float* xr = x + (size_t)t * DD;
  __shared__ float logits[E_N];
  int lane = threadIdx.x & 63, wid = threadIdx.x >> 6;
  for (int ee = 0; ee < 4; ++ee) {
    int e = wid * 4 + ee;
    const float* wr = rw + (size_t)e * DD;
    float p = 0.f;
    for (int d = lane; d < DD; d += 64) p += xr[d] * wr[d];
#pragma unroll
    for (int off = 32; off > 0; off >>= 1) p += __shfl_down(p, off);
    if (lane == 0) logits[e] = p;
  }
  __syncthreads();
  if (threadIdx.x == 0) {
    float mx = -1e30f;
    for (int e = 0; e < E_N; ++e) mx = fmaxf(mx, logits[e]);
    float pe[E_N];
    for (int e = 0; e < E_N; ++e) pe[e] = __expf(logits[e] - mx);
    int idx[TOPK]; float val[TOPK]; float s4 = 0.f;
    unsigned used = 0;
    for (int k = 0; k < TOPK; ++k) {
      int bi = 0; float bv = -1.f;
      for (int e = 0; e < E_N; ++e)
        if (!((used >> e) & 1) && pe[e] > bv) { bv = pe[e]; bi = e; }
      used |= 1u << bi; idx[k] = bi; val[k] = bv; s4 += bv;
    }
    float inv = 1.f / s4;
    for (int k = 0; k < TOPK; ++k) {
      int e2 = idx[k];
      int pos = atomicAdd(&cnt[e2], 1);
      list[e2 * TT + pos] = t * 4 + k;
      tw[t * 4 + k] = val[k] * inv;
    }
  }
}

// ---------------- fused gate+up grouped GEMM ----------------
// LDS per buf: A[128][32] (4096 us) + GU[128][64] (8192 us, G chunks 0-3 | U chunks 4-7)
__global__ __launch_bounds__(256, 2) void gu_kernel(
    const unsigned short* __restrict__ Xb,
    const unsigned short* __restrict__ WgT,  // [E][Ntot][Ktot] bf16
    const unsigned short* __restrict__ WuT,
    unsigned short* __restrict__ H,
    const int* __restrict__ list, const int* __restrict__ cnt,
    int Ktot, int Ntot, int Mfixed) {
  int bm, bn, e;
  swz_block(bm, bn, e);
  int M = cnt ? cnt[e] : Mfixed;
  int m0 = bm * BM;
  if (m0 >= M) return;
  int n0 = bn * BN;
  const unsigned short* Bg0 = WgT + (size_t)e * Ktot * Ntot;
  const unsigned short* Bu0 = WuT + (size_t)e * Ktot * Ntot;
  const int* lst = list ? (list + e * TT) : nullptr;

  __shared__ __align__(16) unsigned short lds[3][12288];

  int tid = threadIdx.x, lane = tid & 63, w = tid >> 6;

  // A staging: 2 issues/wave; issue J covers rows J*16..+15 (64B rows, 4 chunks)
  const unsigned short* pA[2];
#pragma unroll
  for (int q = 0; q < 2; ++q) {
    int J = w * 2 + q;
    int row = J * 16 + (lane >> 2);
    int c = lane & 3;
    int cs = c ^ (row & 3);
    int ar = min(m0 + row, M - 1);
    int tok = lst ? (lst[ar] >> 2) : ar;
    pA[q] = Xb + (size_t)tok * Ktot + cs * 8;
  }
  // GU staging: 4 issues/wave; issue J covers rows J*8..+7 (128B rows, 8 chunks)
  const unsigned short* pGU[4];
#pragma unroll
  for (int q = 0; q < 4; ++q) {
    int J = w * 4 + q;
    int row = J * 8 + (lane >> 3);
    int c = lane & 7;
    int sc = c ^ (row & 7);
    pGU[q] = (sc < 4) ? (Bg0 + (size_t)(n0 + row) * Ktot + sc * 8)
                      : (Bu0 + (size_t)(n0 + row) * Ktot + (sc - 4) * 8);
  }

  auto issue = [&](int kt, int buf) {
    int koff = kt * BK;
    unsigned short* dA = &lds[buf][0];
    unsigned short* dGU = &lds[buf][4096];
#pragma unroll
    for (int q = 0; q < 2; ++q)
      GLOAD16(pA[q] + koff, dA + (w * 2 + q) * 512);
#pragma unroll
    for (int q = 0; q < 4; ++q)
      GLOAD16(pGU[q] + koff, dGU + (w * 4 + q) * 512);
  };

  int wr = (w >> 1) * 64, wc = (w & 1) * 64;
  int cg = lane >> 4;  // 0..3
  int aoff[4], goff[4], uoff[4];
#pragma unroll
  for (int m = 0; m < 4; ++m) {
    int r = wr + m * 16 + (lane & 15);
    aoff[m] = r * 32 + ((cg ^ (r & 3)) * 8);
  }
#pragma unroll
  for (int n = 0; n < 4; ++n) {
    int r = wc + n * 16 + (lane & 15);
    goff[n] = r * 64 + ((cg ^ (r & 7)) * 8);
    uoff[n] = r * 64 + (((cg + 4) ^ (r & 7)) * 8);
  }

  f32x4 accG[4][4] = {};
  f32x4 accU[4][4] = {};

  auto compute = [&](int buf) {
    const unsigned short* A = &lds[buf][0];
    const unsigned short* GU = &lds[buf][4096];
    bf16x8 a[4], g[4], u[4];
#pragma unroll
    for (int m = 0; m < 4; ++m)
      a[m] = __builtin_bit_cast(bf16x8, *reinterpret_cast<const uint4*>(A + aoff[m]));
#pragma unroll
    for (int n = 0; n < 4; ++n) {
      g[n] = __builtin_bit_cast(bf16x8, *reinterpret_cast<const uint4*>(GU + goff[n]));
      u[n] = __builtin_bit_cast(bf16x8, *reinterpret_cast<const uint4*>(GU + uoff[n]));
    }
#pragma unroll
    for (int m = 0; m < 4; ++m)
#pragma unroll
      for (int n = 0; n < 4; ++n) {
        accG[m][n] = __builtin_amdgcn_mfma_f32_16x16x32_bf16(a[m], g[n], accG[m][n], 0, 0, 0);
        accU[m][n] = __builtin_amdgcn_mfma_f32_16x16x32_bf16(a[m], u[n], accU[m][n], 0, 0, 0);
      }
  };

  int nk = Ktot / BK;
  VMW(0); SCHED0();
  issue(0, 0);
  issue(1, 1);
  for (int kt = 0; kt < nk; ++kt) {
    if (kt + 2 < nk) { issue(kt + 2, (kt + 2) % 3); VMW(12); }
    else if (kt + 1 < nk) { VMW(6); }
    else { VMW(0); }
    SCHED0();
    SBAR(); SCHED0();
    compute(kt % 3);
    SCHED0();
    SBAR(); SCHED0();
  }

  // epilogue: h = silu(g)*u -> bf16 at row=code
#pragma unroll
  for (int m = 0; m < 4; ++m) {
#pragma unroll
    for (int r = 0; r < 4; ++r) {
      int lr = wr + m * 16 + (lane >> 4) * 4 + r;
      int grow = m0 + lr;
      if (grow < M) {
        int code = lst ? lst[grow] : grow;
        unsigned short* Hp = H + (size_t)code * Ntot + n0 + wc + (lane & 15);
#pragma unroll
        for (int n = 0; n < 4; ++n) {
          float gg = accG[m][n][r], uu = accU[m][n][r];
          Hp[n * 16] = f2bf((gg / (1.f + __expf(-gg))) * uu);
        }
      }
    }
  }
}

// ---------------- down grouped GEMM ----------------
// LDS per buf: AB[128][64] (8192 us, A chunks 0-3 | B chunks 4-7)
__global__ __launch_bounds__(256, 3) void dn_kernel(
    const unsigned short* __restrict__ Hb,
    const unsigned short* __restrict__ WT,   // [E][Ntot][Ktot] bf16
    float* __restrict__ Y,
    const int* __restrict__ list, const int* __restrict__ cnt,
    const float* __restrict__ tw, int Ktot, int Ntot, int Mfixed) {
  int bm, bn, e;
  swz_block(bm, bn, e);
  int M = cnt ? cnt[e] : Mfixed;
  int m0 = bm * BM;
  if (m0 >= M) return;
  int n0 = bn * BN;
  const unsigned short* B0 = WT + (size_t)e * Ktot * Ntot;
  const int* lst = list ? (list + e * TT) : nullptr;

  __shared__ __align__(16) unsigned short lds[3][8192];

  int tid = threadIdx.x, lane = tid & 63, w = tid >> 6;

  const unsigned short* pAB[4];
#pragma unroll
  for (int q = 0; q < 4; ++q) {
    int J = w * 4 + q;
    int row = J * 8 + (lane >> 3);
    int c = lane & 7;
    int sc = c ^ (row & 7);
    if (sc < 4) {
      int ar = min(m0 + row, M - 1);
      int code = lst ? lst[ar] : ar;
      pAB[q] = Hb + (size_t)code * Ktot + sc * 8;
    } else {
      pAB[q] = B0 + (size_t)(n0 + row) * Ktot + (sc - 4) * 8;
    }
  }

  auto issue = [&](int kt, int buf) {
    int koff = kt * BK;
    unsigned short* d = &lds[buf][0];
#pragma unroll
    for (int q = 0; q < 4; ++q)
      GLOAD16(pAB[q] + koff, d + (w * 4 + q) * 512);
  };

  int wr = (w >> 1) * 64, wc = (w & 1) * 64;
  int cg = lane >> 4;
  int aoff[4], boff[4];
#pragma unroll
  for (int m = 0; m < 4; ++m) {
    int r = wr + m * 16 + (lane & 15);
    aoff[m] = r * 64 + ((cg ^ (r & 7)) * 8);
  }
#pragma unroll
  for (int n = 0; n < 4; ++n) {
    int r = wc + n * 16 + (lane & 15);
    boff[n] = r * 64 + (((cg + 4) ^ (r & 7)) * 8);
  }

  f32x4 acc[4][4] = {};

  auto compute = [&](int buf) {
    const unsigned short* AB = &lds[buf][0];
    bf16x8 a[4], b[4];
#pragma unroll
    for (int m = 0; m < 4; ++m)
      a[m] = __builtin_bit_cast(bf16x8, *reinterpret_cast<const uint4*>(AB + aoff[m]));
#pragma unroll
    for (int n = 0; n < 4; ++n)
      b[n] = __builtin_bit_cast(bf16x8, *reinterpret_cast<const uint4*>(AB + boff[n]));
#pragma unroll
    for (int m = 0; m < 4; ++m)
#pragma unroll
      for (int n = 0; n < 4; ++n)
        acc[m][n] = __builtin_amdgcn_mfma_f32_16x16x32_bf16(a[m], b[n], acc[m][n], 0, 0, 0);
  };

  int nk = Ktot / BK;
  VMW(0); SCHED0();
  issue(0, 0);
  issue(1, 1);
  for (int kt = 0; kt < nk; ++kt) {
    if (kt + 2 < nk) { issue(kt + 2, (kt + 2) % 3); VMW(8); }
    else if (kt + 1 < nk) { VMW(4); }
    else { VMW(0); }
    SCHED0();
    SBAR(); SCHED0();
    compute(kt % 3);
    SCHED0();
    SBAR(); SCHED0();
  }

#pragma unroll
  for (int m = 0; m < 4; ++m) {
#pragma unroll
    for (int r = 0; r < 4; ++r) {
      int lr = wr + m * 16 + (lane >> 4) * 4 + r;
      int grow = m0 + lr;
      if (grow < M) {
        int code = lst ? lst[grow] : grow;
        float scale = tw ? tw[code] : 1.f;
        float* Yp = Y + (size_t)code * Ntot + n0 + wc + (lane & 15);
#pragma unroll
        for (int n = 0; n < 4; ++n) Yp[n * 16] = acc[m][n][r] * scale;
      }
    }
  }
}

// ---------------- combine ----------------
__global__ __launch_bounds__(256) void combine_kernel(const float* __restrict__ Y,
                                                      const float* __restrict__ Ys,
                                                      float* __restrict__ out) {
  size_t i = ((size_t)blockIdx.x * 256 + threadIdx.x) * 4;
  size_t t = i / DD;
  int d = (int)(i % DD);
  float4 a = *reinterpret_cast<const float4*>(Ys + i);
#pragma unroll
  for (int k = 0; k < 4; ++k) {
    float4 v = *reinterpret_cast<const float4*>(Y + (t * 4 + k) * (size_t)DD + d);
    a.x += v.x; a.y += v.y; a.z += v.z; a.w += v.w;
  }
  *reinterpret_cast<float4*>(out + i) = a;
}

extern "C" void kernel_launch(void* const* d_in, const int* in_sizes, int n_in,
                              void* d_out, int out_size, void* d_ws, size_t ws_size,
                              hipStream_t stream) {
  const float* x  = (const float*)d_in[0];
  const float* rw = (const float*)d_in[1];
  const float* wg = (const float*)d_in[2];
  const float* wu = (const float*)d_in[3];
  const float* wd = (const float*)d_in[4];
  const float* sg = (const float*)d_in[5];
  const float* su = (const float*)d_in[6];
  const float* sd = (const float*)d_in[7];
  float* out = (float*)d_out;

  char* ws = (char*)d_ws;
  size_t off = 0;
  auto alloc = [&](size_t bytes) {
    off = (off + 255) & ~(size_t)255;
    void* p = ws + off;
    off += bytes;
    return p;
  };
  unsigned short* W1 = (unsigned short*)alloc((size_t)E_N * FF * DD * 2);   // 136 MB
  unsigned short* W2 = (unsigned short*)alloc((size_t)E_N * FF * DD * 2);   // 136 MB
  unsigned short* W3 = (unsigned short*)alloc((size_t)FSS * DD * 2);        // 17 MB
  unsigned short* W4 = (unsigned short*)alloc((size_t)FSS * DD * 2);        // 17 MB
  unsigned short* Xb = (unsigned short*)alloc((size_t)TT * DD * 2);
  unsigned short* Hx = (unsigned short*)alloc((size_t)4 * TT * FF * 2);
  unsigned short* Hs = (unsigned short*)alloc((size_t)TT * FSS * 2);
  float* Y  = (float*)alloc((size_t)4 * TT * DD * 4);
  float* Ys = (float*)alloc((size_t)TT * DD * 4);
  float* tw = (float*)alloc((size_t)4 * TT * 4);
  int* cnt  = (int*)alloc(E_N * 4);
  int* list = (int*)alloc((size_t)E_N * TT * 4);
  (void)ws_size; (void)in_sizes; (void)n_in; (void)out_size;

  hipMemsetAsync(cnt, 0, E_N * 4, stream);
  cvt_bf16_kernel<<<TT * DD / 4 / 256, 256, 0, stream>>>(x, Xb);
  router_kernel<<<TT, 256, 0, stream>>>(x, rw, cnt, list, tw);

  // --- gate/up weight transposes: [D][F(S)] -> [F(S)][D] bf16 ---
  tcvt_kernel<<<dim3(DD / 64, FF / 64, E_N), 256, 0, stream>>>(wg, W1, DD, FF);
  tcvt_kernel<<<dim3(DD / 64, FF / 64, E_N), 256, 0, stream>>>(wu, W2, DD, FF);
  tcvt_kernel<<<dim3(DD / 64, FSS / 64, 1), 256, 0, stream>>>(sg, W3, DD, FSS);
  tcvt_kernel<<<dim3(DD / 64, FSS / 64, 1), 256, 0, stream>>>(su, W4, DD, FSS);

  // --- gate+up GEMMs ---
  gu_kernel<<<dim3(TT / BM, FF / BN, E_N), 256, 0, stream>>>(
      Xb, W1, W2, Hx, list, cnt, DD, FF, 0);
  gu_kernel<<<dim3(TT / BM, FSS / BN, 1), 256, 0, stream>>>(
      Xb, W3, W4, Hs, nullptr, nullptr, DD, FSS, TT);

  // --- down weight transposes: [F(S)][D] -> [D][F(S)] bf16 (reuse W1/W2) ---
  tcvt_kernel<<<dim3(FF / 64, DD / 64, E_N), 256, 0, stream>>>(wd, W1, FF, DD);
  tcvt_kernel<<<dim3(FSS / 64, DD / 64, 1), 256, 0, stream>>>(sd, W2, FSS, DD);

  // --- down GEMMs ---
  dn_kernel<<<dim3(TT / BM, DD / BN, E_N), 256, 0, stream>>>(
      Hx, W1, Y, list, cnt, tw, FF, DD, 0);
  dn_kernel<<<dim3(TT / BM, DD / BN, 1), 256, 0, stream>>>(
      Hs, W2, Ys, nullptr, nullptr, nullptr, FSS, DD, TT);

  combine_kernel<<<TT * DD / 4 / 256, 256, 0, stream>>>(Y, Ys, out);
}